// Round 16
// baseline (461.760 us; speedup 1.0000x reference)
//
#include <hip/hip_runtime.h>
#include <cmath>

#define N      50000
#define E      800000
#define NFEAT  128
#define NHID   128
#define NCLASS 40
#define NUM_HOPS 4
#define NF     (N * NHID)   // 6,400,000 elements per h buffer
#define NB     ((N + 255) / 256)   // 196 scan blocks == buckets (256 rows each)
#define EVCAP  (E + 3 * N)  // padded edge-array capacity (pad to multiple of 4)
#define XSTR   132          // LDS row stride in attn kernel (conflict break)

typedef __attribute__((ext_vector_type(8))) short bf16x8;   // 8 bf16 in 4 VGPRs
typedef __attribute__((ext_vector_type(4))) float f32x4;

// bf16 helpers (RTNE)
__device__ __forceinline__ unsigned bf16pack(float a, float b) {
    unsigned ua = __float_as_uint(a), ub = __float_as_uint(b);
    ua = (ua + 0x7fffu + ((ua >> 16) & 1u)) >> 16;
    ub = (ub + 0x7fffu + ((ub >> 16) & 1u)) >> 16;
    return ua | (ub << 16);
}
__device__ __forceinline__ unsigned short bf16s(float x) {
    unsigned u = __float_as_uint(x);
    u = (u + 0x7fffu + ((u >> 16) & 1u)) >> 16;
    return (unsigned short)u;
}
__device__ __forceinline__ float bf16lo(unsigned u) { return __uint_as_float(u << 16); }
__device__ __forceinline__ float bf16hi(unsigned u) { return __uint_as_float(u & 0xffff0000u); }

// ---------------- CSR build (rows padded to multiple of 4 edges) ----------------

__global__ void k_hist(const int* __restrict__ row, int* __restrict__ cnt) {
    int e = blockIdx.x * blockDim.x + threadIdx.x;
    if (e < E) atomicAdd(&cnt[row[e]], 1);
}

__global__ void k_bsum(const int* __restrict__ cnt, int* __restrict__ bsum) {
    int t = threadIdx.x;
    int i = blockIdx.x * 256 + t;
    int v = (i < N) ? ((cnt[i] + 3) & ~3) : 0;
    for (int off = 32; off; off >>= 1) v += __shfl_xor(v, off);
    __shared__ int ws[4];
    if ((t & 63) == 0) ws[t >> 6] = v;
    __syncthreads();
    if (t == 0) bsum[blockIdx.x] = ws[0] + ws[1] + ws[2] + ws[3];
}

__global__ void k_scanb(const int* __restrict__ bsum, int* __restrict__ boff) {
    __shared__ int ws[4];
    int t = threadIdx.x;
    int v = (t < NB) ? bsum[t] : 0;
    int lane = t & 63, w = t >> 6;
    int incl = v;
    for (int off = 1; off < 64; off <<= 1) {
        int u = __shfl_up(incl, off);
        if (lane >= off) incl += u;
    }
    if (lane == 63) ws[w] = incl;
    __syncthreads();
    int woff = 0;
    for (int k = 0; k < w; ++k) woff += ws[k];
    if (t < NB) boff[t] = incl - v + woff;
}

__global__ void k_expand(const int* __restrict__ cnt, const int* __restrict__ boff,
                         int* __restrict__ rp) {
    __shared__ int ws[4];
    int t = threadIdx.x;
    int i = blockIdx.x * 256 + t;
    int pc = (i < N) ? ((cnt[i] + 3) & ~3) : 0;
    int lane = t & 63, w = t >> 6;
    int incl = pc;
    for (int off = 1; off < 64; off <<= 1) {
        int u = __shfl_up(incl, off);
        if (lane >= off) incl += u;
    }
    if (lane == 63) ws[w] = incl;
    __syncthreads();
    int woff = 0;
    for (int k = 0; k < w; ++k) woff += ws[k];
    int r = boff[blockIdx.x] + incl - pc + woff;
    if (i < N) {
        rp[i] = r;
        if (i == N - 1) rp[N] = r + pc;
    }
}

// bucket cursors: one int per bucket, padded to 64 B (16 ints) to avoid
// same-line atomic serialization.
__global__ void k_initb(const int* __restrict__ rp, int* __restrict__ bcur) {
    int t = threadIdx.x;
    if (t < NB) bcur[t * 16] = rp[t * 256];
}

// Pass 1: partition edges into row-range buckets. Appends are sequential per
// bucket pointer -> cache lines fill completely before write-back.
__global__ void k_bucket(const int* __restrict__ row, const int* __restrict__ col,
                         const float* __restrict__ val,
                         int* __restrict__ bcur, uint2* __restrict__ stage) {
    int e = blockIdx.x * blockDim.x + threadIdx.x;
    if (e < E) {
        int r = row[e];
        int p = atomicAdd(&bcur[(r >> 8) * 16], 1);
        stage[p] = make_uint2(((unsigned)r << 16) | (unsigned)col[e],
                              __float_as_uint(val[e]));
    }
}

// Pass 2: one block per bucket; LDS per-row cursors; final ev writes land in
// the bucket's ~17 KB contiguous window (L2-resident until lines fill).
// Packed edge: low 16 bits = col, high 16 = bf16(val). Pads stay memset-0.
__global__ __launch_bounds__(256) void k_scatter2(const int* __restrict__ rp,
                                                  const int* __restrict__ bcur,
                                                  const uint2* __restrict__ stage,
                                                  unsigned* __restrict__ ev) {
    __shared__ int cur[256];
    int b = blockIdx.x;
    int t = threadIdx.x;
    int gr = b * 256 + t;
    cur[t] = (gr < N) ? rp[gr] : 0;
    __syncthreads();
    int lo = rp[b * 256];
    int hi = bcur[b * 16];           // lo + actual (unpadded) edge count
    for (int i = lo + t; i < hi; i += 256) {
        uint2 rec = stage[i];
        int local = (rec.x >> 16) & 255;
        unsigned v = rec.y;
        v = (v + 0x7fffu + ((v >> 16) & 1u)) & 0xffff0000u;   // RTNE bf16 high half
        int p = atomicAdd(&cur[local], 1);
        ev[p] = (rec.x & 0xffffu) | v;
    }
}

// ---------------- SpMM: 4 rows per wave, bf16 x, packed edges, f32 acc, bf16 out ----------------

__global__ void k_spmm(const int* __restrict__ rp, const unsigned* __restrict__ ev,
                       const unsigned short* __restrict__ xb,
                       unsigned short* __restrict__ y) {
    int wid  = (blockIdx.x * blockDim.x + threadIdx.x) >> 6;   // wave id
    if (wid >= N / 4) return;
    int lane = threadIdx.x & 63;
    int q  = lane >> 4;       // quarter 0..3
    int ql = lane & 15;       // lane within quarter
    int row = wid * 4 + q;
    int beg = rp[row], end = rp[row + 1];      // multiples of 4
    float a0 = 0.f, a1 = 0.f, a2 = 0.f, a3 = 0.f;
    float a4 = 0.f, a5 = 0.f, a6 = 0.f, a7 = 0.f;
    const uint4* xq = (const uint4*)xb;        // row r -> base index r*16
#define ACC8(g, v)                                                            \
    do {                                                                      \
        a0 = fmaf((v), bf16lo((g).x), a0); a1 = fmaf((v), bf16hi((g).x), a1); \
        a2 = fmaf((v), bf16lo((g).y), a2); a3 = fmaf((v), bf16hi((g).y), a3); \
        a4 = fmaf((v), bf16lo((g).z), a4); a5 = fmaf((v), bf16hi((g).z), a5); \
        a6 = fmaf((v), bf16lo((g).w), a6); a7 = fmaf((v), bf16hi((g).w), a7); \
    } while (0)
    int j = beg;
    for (; j + 8 <= end; j += 8) {
        uint4 p0 = *(const uint4*)(ev + j);
        uint4 p1 = *(const uint4*)(ev + j + 4);
        uint4 g0 = xq[(size_t)(p0.x & 0xffffu) * 16 + ql];
        uint4 g1 = xq[(size_t)(p0.y & 0xffffu) * 16 + ql];
        uint4 g2 = xq[(size_t)(p0.z & 0xffffu) * 16 + ql];
        uint4 g3 = xq[(size_t)(p0.w & 0xffffu) * 16 + ql];
        uint4 g4 = xq[(size_t)(p1.x & 0xffffu) * 16 + ql];
        uint4 g5 = xq[(size_t)(p1.y & 0xffffu) * 16 + ql];
        uint4 g6 = xq[(size_t)(p1.z & 0xffffu) * 16 + ql];
        uint4 g7 = xq[(size_t)(p1.w & 0xffffu) * 16 + ql];
        ACC8(g0, bf16hi(p0.x));
        ACC8(g1, bf16hi(p0.y));
        ACC8(g2, bf16hi(p0.z));
        ACC8(g3, bf16hi(p0.w));
        ACC8(g4, bf16hi(p1.x));
        ACC8(g5, bf16hi(p1.y));
        ACC8(g6, bf16hi(p1.z));
        ACC8(g7, bf16hi(p1.w));
    }
    if (j < end) {   // exactly 4 remain
        uint4 p0 = *(const uint4*)(ev + j);
        uint4 g0 = xq[(size_t)(p0.x & 0xffffu) * 16 + ql];
        uint4 g1 = xq[(size_t)(p0.y & 0xffffu) * 16 + ql];
        uint4 g2 = xq[(size_t)(p0.z & 0xffffu) * 16 + ql];
        uint4 g3 = xq[(size_t)(p0.w & 0xffffu) * 16 + ql];
        ACC8(g0, bf16hi(p0.x));
        ACC8(g1, bf16hi(p0.y));
        ACC8(g2, bf16hi(p0.z));
        ACC8(g3, bf16hi(p0.w));
    }
#undef ACC8
    uint4 o;
    o.x = bf16pack(a0, a1);
    o.y = bf16pack(a2, a3);
    o.z = bf16pack(a4, a5);
    o.w = bf16pack(a6, a7);
    ((uint4*)(y + (size_t)row * NHID))[ql] = o;
}

// ---------------- f32 -> bf16 converts ----------------

__global__ void k_cvt(const float* __restrict__ f, unsigned short* __restrict__ fb) {
    int i = blockIdx.x * blockDim.x + threadIdx.x;   // one float4 per thread
    if (i >= NF / 4) return;
    float4 v = ((const float4*)f)[i];
    uint2 o;
    o.x = bf16pack(v.x, v.y);
    o.y = bf16pack(v.z, v.w);
    ((uint2*)fb)[i] = o;
}

// W (4 x 128 x 128, [hop][k][n]) -> transposed bf16 Wbt [hop][n][k]
__global__ void k_cvt_w(const float* __restrict__ Wg, unsigned short* __restrict__ Wbt) {
    int idx = blockIdx.x * blockDim.x + threadIdx.x;
    if (idx >= NUM_HOPS * NHID * NHID) return;
    int i = idx >> 14;            // hop
    int rem = idx & 16383;
    int n = rem >> 7;             // out row (col of W)
    int k = rem & 127;            // out col (row of W)
    Wbt[idx] = bf16s(Wg[(i << 14) + k * NHID + n]);
}

// ---------------- GEMM via MFMA 16x16x32 bf16: h = relu(tmp @ W), + hop score ----------------

__global__ __launch_bounds__(256) void k_gemm(const unsigned short* __restrict__ tmpb,
                                              const unsigned short* __restrict__ Wbt,
                                              const float* __restrict__ att_w,
                                              unsigned short* __restrict__ yb,
                                              float* __restrict__ Sh) {
    int t = threadIdx.x;
    int w = t >> 6;
    int lane = t & 63;
    int quad = lane >> 4;
    int l15 = lane & 15;
    int rowb = blockIdx.x * 64 + w * 16;      // wave's 16-row base

    bf16x8 af[4];
#pragma unroll
    for (int s = 0; s < 4; ++s) {
        uint4 ua = *(const uint4*)(tmpb + ((size_t)(rowb + l15) * NHID + s * 32 + quad * 8));
        af[s] = __builtin_bit_cast(bf16x8, ua);
    }

    f32x4 acc[8];
#pragma unroll
    for (int nt = 0; nt < 8; ++nt) acc[nt] = (f32x4){0.f, 0.f, 0.f, 0.f};

#pragma unroll
    for (int nt = 0; nt < 8; ++nt) {
#pragma unroll
        for (int s = 0; s < 4; ++s) {
            uint4 ub = *(const uint4*)(Wbt + ((size_t)(nt * 16 + l15) * NHID + s * 32 + quad * 8));
            bf16x8 bfv = __builtin_bit_cast(bf16x8, ub);
            acc[nt] = __builtin_amdgcn_mfma_f32_16x16x32_bf16(af[s], bfv, acc[nt], 0, 0, 0);
        }
    }

    float whl[8];
#pragma unroll
    for (int nt = 0; nt < 8; ++nt) whl[nt] = att_w[nt * 16 + l15];

    float scr[4] = {0.f, 0.f, 0.f, 0.f};
#pragma unroll
    for (int nt = 0; nt < 8; ++nt) {
#pragma unroll
        for (int r = 0; r < 4; ++r) {
            float v = fmaxf(acc[nt][r], 0.f);
            scr[r] = fmaf(v, whl[nt], scr[r]);
            int grow = rowb + quad * 4 + r;
            if (grow < N)
                yb[(size_t)grow * NHID + nt * 16 + l15] = bf16s(v);
        }
    }
#pragma unroll
    for (int r = 0; r < 4; ++r) {
        float p = scr[r];
        p += __shfl_xor(p, 1);
        p += __shfl_xor(p, 2);
        p += __shfl_xor(p, 4);
        p += __shfl_xor(p, 8);
        int grow = rowb + quad * 4 + r;
        if (l15 == 0 && grow < N) Sh[grow] = p;
    }
}

// ---------------- Feature score: fs[node] = f[node] . w_f (f32 features) ----------------

__global__ void k_fscore(const float* __restrict__ f, const float* __restrict__ att_w,
                         float* __restrict__ fs) {
    int node = (blockIdx.x * blockDim.x + threadIdx.x) >> 6;
    if (node >= N) return;
    int lane = threadIdx.x & 63;
    const float2 wf = ((const float2*)(att_w + NHID))[lane];
    const float2 fv = ((const float2*)(f + (size_t)node * NFEAT))[lane];
    float s = fv.x * wf.x + fv.y * wf.y;
    for (int off = 32; off; off >>= 1) s += __shfl_xor(s, off);
    if (lane == 0) fs[node] = s;
}

// ---------------- Attention + output head (64 nodes/block, bf16 h input) ----------------

__global__ __launch_bounds__(256) void k_attn_final(const unsigned short* __restrict__ hb,
                                                    const float* __restrict__ S,
                                                    const float* __restrict__ fs,
                                                    const float* __restrict__ att_b,
                                                    const float* __restrict__ fc_w,
                                                    const float* __restrict__ fc_b,
                                                    float* __restrict__ out) {
    __shared__ float xs[64 * XSTR];
    __shared__ float wv[4][64];
    int t = threadIdx.x;
    int base = blockIdx.x * 64;

    if (t < 64) {
        int node = base + t;
        if (node < N) {
            float b = att_b[0] + fs[node];
            float g0 = 1.f / (1.f + __expf(-(S[0 * N + node] + b)));
            float g1 = 1.f / (1.f + __expf(-(S[1 * N + node] + b)));
            float g2 = 1.f / (1.f + __expf(-(S[2 * N + node] + b)));
            float g3 = 1.f / (1.f + __expf(-(S[3 * N + node] + b)));
            float m = fmaxf(fmaxf(g0, g1), fmaxf(g2, g3));
            float e0 = __expf(g0 - m), e1 = __expf(g1 - m);
            float e2 = __expf(g2 - m), e3 = __expf(g3 - m);
            float inv = 1.f / (e0 + e1 + e2 + e3);
            wv[0][t] = e0 * inv; wv[1][t] = e1 * inv;
            wv[2][t] = e2 * inv; wv[3][t] = e3 * inv;
        } else {
            wv[0][t] = 0.f; wv[1][t] = 0.f; wv[2][t] = 0.f; wv[3][t] = 0.f;
        }
    }
    __syncthreads();

#pragma unroll
    for (int qq = 0; qq < 4; ++qq) {
        int idx = qq * 256 + t;     // 0..1023
        int nl = idx >> 4;          // local node 0..63
        int d8 = idx & 15;          // uint4 (8-elem) index within row
        int node = base + nl;
        float o[8] = {0.f, 0.f, 0.f, 0.f, 0.f, 0.f, 0.f, 0.f};
        if (node < N) {
            float w0 = wv[0][nl], w1 = wv[1][nl], w2 = wv[2][nl], w3 = wv[3][nl];
            uint4 u0 = ((const uint4*)(hb + 0 * (size_t)NF + (size_t)node * NHID))[d8];
            uint4 u1 = ((const uint4*)(hb + 1 * (size_t)NF + (size_t)node * NHID))[d8];
            uint4 u2 = ((const uint4*)(hb + 2 * (size_t)NF + (size_t)node * NHID))[d8];
            uint4 u3 = ((const uint4*)(hb + 3 * (size_t)NF + (size_t)node * NHID))[d8];
            o[0] = w0 * bf16lo(u0.x) + w1 * bf16lo(u1.x) + w2 * bf16lo(u2.x) + w3 * bf16lo(u3.x);
            o[1] = w0 * bf16hi(u0.x) + w1 * bf16hi(u1.x) + w2 * bf16hi(u2.x) + w3 * bf16hi(u3.x);
            o[2] = w0 * bf16lo(u0.y) + w1 * bf16lo(u1.y) + w2 * bf16lo(u2.y) + w3 * bf16lo(u3.y);
            o[3] = w0 * bf16hi(u0.y) + w1 * bf16hi(u1.y) + w2 * bf16hi(u2.y) + w3 * bf16hi(u3.y);
            o[4] = w0 * bf16lo(u0.z) + w1 * bf16lo(u1.z) + w2 * bf16lo(u2.z) + w3 * bf16lo(u3.z);
            o[5] = w0 * bf16hi(u0.z) + w1 * bf16hi(u1.z) + w2 * bf16hi(u2.z) + w3 * bf16hi(u3.z);
            o[6] = w0 * bf16lo(u0.w) + w1 * bf16lo(u1.w) + w2 * bf16lo(u2.w) + w3 * bf16lo(u3.w);
            o[7] = w0 * bf16hi(u0.w) + w1 * bf16hi(u1.w) + w2 * bf16hi(u2.w) + w3 * bf16hi(u3.w);
        }
        float* xp = &xs[nl * XSTR + (d8 << 3)];
        *(float4*)xp       = make_float4(o[0], o[1], o[2], o[3]);
        *(float4*)(xp + 4) = make_float4(o[4], o[5], o[6], o[7]);
    }
    __syncthreads();

    int cq = t & 15;                     // col quad (active: cq<10)
    int rg = t >> 4;                     // row group: rows rg*4 .. rg*4+3
    int cb = (cq < 10) ? (cq << 2) : 36; // clamped col base: loads stay in-bounds
    float4 bias = *(const float4*)(fc_b + cb);
    float4 acc[4];
#pragma unroll
    for (int r = 0; r < 4; ++r) acc[r] = bias;
    for (int k4 = 0; k4 < NHID / 4; ++k4) {
        float4 w0 = *(const float4*)(fc_w + (size_t)(4 * k4 + 0) * NCLASS + cb);
        float4 w1 = *(const float4*)(fc_w + (size_t)(4 * k4 + 1) * NCLASS + cb);
        float4 w2 = *(const float4*)(fc_w + (size_t)(4 * k4 + 2) * NCLASS + cb);
        float4 w3 = *(const float4*)(fc_w + (size_t)(4 * k4 + 3) * NCLASS + cb);
#pragma unroll
        for (int r = 0; r < 4; ++r) {
            float4 xv = *(const float4*)&xs[(rg * 4 + r) * XSTR + (k4 << 2)];
            acc[r].x = fmaf(xv.x, w0.x, acc[r].x);
            acc[r].y = fmaf(xv.x, w0.y, acc[r].y);
            acc[r].z = fmaf(xv.x, w0.z, acc[r].z);
            acc[r].w = fmaf(xv.x, w0.w, acc[r].w);
            acc[r].x = fmaf(xv.y, w1.x, acc[r].x);
            acc[r].y = fmaf(xv.y, w1.y, acc[r].y);
            acc[r].z = fmaf(xv.y, w1.z, acc[r].z);
            acc[r].w = fmaf(xv.y, w1.w, acc[r].w);
            acc[r].x = fmaf(xv.z, w2.x, acc[r].x);
            acc[r].y = fmaf(xv.z, w2.y, acc[r].y);
            acc[r].z = fmaf(xv.z, w2.z, acc[r].z);
            acc[r].w = fmaf(xv.z, w2.w, acc[r].w);
            acc[r].x = fmaf(xv.w, w3.x, acc[r].x);
            acc[r].y = fmaf(xv.w, w3.y, acc[r].y);
            acc[r].z = fmaf(xv.w, w3.z, acc[r].z);
            acc[r].w = fmaf(xv.w, w3.w, acc[r].w);
        }
    }
#pragma unroll
    for (int r = 0; r < 4; ++r) {
        int nd = base + rg * 4 + r;
        float mloc = (cq < 10)
            ? fmaxf(fmaxf(acc[r].x, acc[r].y), fmaxf(acc[r].z, acc[r].w))
            : -INFINITY;
        float m = mloc;
        m = fmaxf(m, __shfl_xor(m, 1));
        m = fmaxf(m, __shfl_xor(m, 2));
        m = fmaxf(m, __shfl_xor(m, 4));
        m = fmaxf(m, __shfl_xor(m, 8));
        float sloc = (cq < 10)
            ? (__expf(acc[r].x - m) + __expf(acc[r].y - m) +
               __expf(acc[r].z - m) + __expf(acc[r].w - m))
            : 0.f;
        float s = sloc;
        s += __shfl_xor(s, 1);
        s += __shfl_xor(s, 2);
        s += __shfl_xor(s, 4);
        s += __shfl_xor(s, 8);
        float ls = m + logf(s);
        if (cq < 10 && nd < N) {
            float4 o;
            o.x = acc[r].x - ls;
            o.y = acc[r].y - ls;
            o.z = acc[r].z - ls;
            o.w = acc[r].w - ls;
            *(float4*)(out + (size_t)nd * NCLASS + cb) = o;
        }
    }
}

// ---------------- launch ----------------

extern "C" void kernel_launch(void* const* d_in, const int* in_sizes, int n_in,
                              void* d_out, int out_size, void* d_ws, size_t ws_size,
                              hipStream_t stream) {
    const float* features = (const float*)d_in[0];
    const int*   erow     = (const int*)d_in[1];
    const int*   ecol     = (const int*)d_in[2];
    const float* eval_    = (const float*)d_in[3];
    const float* Wg       = (const float*)d_in[4];
    const float* att_w    = (const float*)d_in[5];
    const float* att_b    = (const float*)d_in[6];
    const float* fc_w     = (const float*)d_in[7];
    const float* fc_b     = (const float*)d_in[8];
    float*       out      = (float*)d_out;

    // workspace layout (4-byte slots; ~90 MB)
    const size_t SLOTS = (size_t)NF / 2        // tmpb (bf16 spmm result)
                       + 2 * (size_t)NF        // hbb: 4 x NF bf16
                       + (size_t)NF / 2        // fb: NF bf16
                       + 32768                 // Wbt: 4*128*128 bf16
                       + 2 * (size_t)EVCAP     // stage (uint2)
                       + (size_t)EVCAP         // ev (packed u32)
                       + (size_t)NB * 16       // bcur (64B-padded bucket cursors)
                       + (N + 4)               // rp
                       + N                     // cnt (reused as fs)
                       + 2 * NB                // bsum, boff
                       + 4 * (size_t)N;        // S
    if (ws_size < SLOTS * 4) return;  // readable failure instead of OOB crash

    unsigned short* tmpb = (unsigned short*)d_ws;                // NF bf16
    unsigned short* hbb  = tmpb + (size_t)NF;                    // 4*NF bf16
    unsigned short* fb   = hbb + 4 * (size_t)NF;                 // NF bf16
    unsigned short* Wbt  = fb + (size_t)NF;                      // 65536 bf16
    uint2*          stage = (uint2*)(Wbt + 65536);               // EVCAP uint2
    unsigned*       ev   = (unsigned*)(stage + EVCAP);           // EVCAP u32
    int*            bcur = (int*)(ev + EVCAP);                   // NB*16
    int*            rp   = bcur + (size_t)NB * 16;               // N+1 (+pad)
    int*            cnt  = rp + (N + 4);                         // N (hist / fs alias)
    int*            bsum = cnt + N;                              // NB
    int*            boff = bsum + NB;                            // NB
    float*          S    = (float*)(boff + NB);                  // 4*N hop scores
    float*          fs   = (float*)cnt;                          // alias after CSR build

    // CSR build (rows padded to x4 with packed-zero edges)
    hipMemsetAsync(cnt, 0, N * sizeof(int), stream);
    hipMemsetAsync(ev, 0, EVCAP * sizeof(unsigned), stream);
    k_hist<<<(E + 255) / 256, 256, 0, stream>>>(erow, cnt);
    k_bsum<<<NB, 256, 0, stream>>>(cnt, bsum);
    k_scanb<<<1, 256, 0, stream>>>(bsum, boff);
    k_expand<<<NB, 256, 0, stream>>>(cnt, boff, rp);
    // two-pass ordered scatter
    k_initb<<<1, 256, 0, stream>>>(rp, bcur);
    k_bucket<<<(E + 255) / 256, 256, 0, stream>>>(erow, ecol, eval_, bcur, stage);
    k_scatter2<<<NB, 256, 0, stream>>>(rp, bcur, stage, ev);

    // feature score (f32), bf16 feature copy, transposed bf16 weights
    k_fscore<<<(N * 64 + 255) / 256, 256, 0, stream>>>(features, att_w, fs);
    k_cvt<<<(NF / 4 + 255) / 256, 256, 0, stream>>>(features, fb);
    k_cvt_w<<<(NUM_HOPS * NHID * NHID + 255) / 256, 256, 0, stream>>>(Wg, Wbt);

    // hops: spmm (bf16 in/out, f32 acc) -> MFMA gemm (bf16 in/out, f32 acc)
    const unsigned short* xb = fb;
    for (int i = 0; i < NUM_HOPS; ++i) {
        k_spmm<<<(N / 4) * 64 / 256, 256, 0, stream>>>(rp, ev, xb, tmpb);
        k_gemm<<<(N + 63) / 64, 256, 0, stream>>>(tmpb, Wbt + (size_t)i * NHID * NHID,
                                                  att_w, hbb + (size_t)i * NF,
                                                  S + (size_t)i * N);
        xb = hbb + (size_t)i * NF;
    }

    // attention + fc + log_softmax (bf16 h input, f32 math)
    k_attn_final<<<(N + 63) / 64, 256, 0, stream>>>(hbb, S, fs, att_b, fc_w, fc_b, out);
}